// Round 1
// baseline (370.532 us; speedup 1.0000x reference)
//
#include <hip/hip_runtime.h>

// CausalSelfAttention: B=4, T=2048, C=1024, H=16, hd=64
// Pipeline: cast->bf16, QKV GEMM (MFMA), flash attention (MFMA), proj GEMM (MFMA)

#define T_SEQ 2048
#define NB 4
#define NH 16
#define CDIM 1024
#define HD 64
#define BH (NB * NH)

typedef float f32x4 __attribute__((ext_vector_type(4)));
typedef __bf16 bf16x8 __attribute__((ext_vector_type(8)));
typedef unsigned short u16x8 __attribute__((ext_vector_type(8)));

__device__ __forceinline__ unsigned short f2b(float f) {
    union { float f; unsigned u; } v; v.f = f;
    unsigned u = v.u;
    u += 0x7FFFu + ((u >> 16) & 1u);   // round-to-nearest-even
    return (unsigned short)(u >> 16);
}

__device__ __forceinline__ f32x4 fzero4() {
    f32x4 z; z[0] = 0.f; z[1] = 0.f; z[2] = 0.f; z[3] = 0.f; return z;
}

// ---------------- prep: fp32 -> bf16 cast (vectorized) ----------------
__global__ __launch_bounds__(256) void cast_f32_bf16_kernel(
        const float* __restrict__ in, unsigned short* __restrict__ out, int n8) {
    int i = blockIdx.x * 256 + threadIdx.x;
    int stride = gridDim.x * 256;
    for (; i < n8; i += stride) {
        const float4* p = reinterpret_cast<const float4*>(in) + (size_t)i * 2;
        float4 a = p[0], b = p[1];
        u16x8 o;
        o[0] = f2b(a.x); o[1] = f2b(a.y); o[2] = f2b(a.z); o[3] = f2b(a.w);
        o[4] = f2b(b.x); o[5] = f2b(b.y); o[6] = f2b(b.z); o[7] = f2b(b.w);
        *(reinterpret_cast<u16x8*>(out) + i) = o;
    }
}

// ---------------- prep: transpose + cast [R][C] f32 -> [C][R] bf16 ----------------
__global__ __launch_bounds__(256) void transpose_cast_kernel(
        const float* __restrict__ in, unsigned short* __restrict__ out, int R, int C) {
    __shared__ unsigned short tile[32][33];
    int tx = threadIdx.x, ty = threadIdx.y;
    int c0 = blockIdx.x * 32, r0 = blockIdx.y * 32;
    for (int rr = ty; rr < 32; rr += 8)
        tile[rr][tx] = f2b(in[(size_t)(r0 + rr) * C + c0 + tx]);
    __syncthreads();
    for (int rr = ty; rr < 32; rr += 8)
        out[(size_t)(c0 + rr) * R + r0 + tx] = tile[tx][rr];
}

// ---------------- GEMM: C[M][N] = A[M][K] @ Bt[N][K]^T + bias ----------------
// EPI=0: write fp32 to outF.  EPI=1: scatter bf16 q/k/v into [B*H][T][HD] buffers.
template <int EPI>
__global__ __launch_bounds__(256) void gemm_bt_kernel(
        const unsigned short* __restrict__ A, const unsigned short* __restrict__ Bt,
        const float* __restrict__ bias, float* __restrict__ outF,
        unsigned short* __restrict__ q_out, unsigned short* __restrict__ k_out,
        unsigned short* __restrict__ v_out, int M, int N, int K) {
    __shared__ alignas(16) unsigned short As[128][40];  // +8 pad: ~2-way banks
    __shared__ alignas(16) unsigned short Bs[128][40];

    int tid = threadIdx.x;
    int wid = tid >> 6, lane = tid & 63;
    int g = lane >> 4, lc = lane & 15;
    int wr = (wid >> 1) * 64, wc = (wid & 1) * 64;
    int m0 = blockIdx.y * 128, n0 = blockIdx.x * 128;

    f32x4 acc[4][4];
#pragma unroll
    for (int m = 0; m < 4; ++m)
#pragma unroll
        for (int n = 0; n < 4; ++n) acc[m][n] = fzero4();

    int arow = tid >> 2;             // 0..63
    int ak = (tid & 3) * 8;          // 0,8,16,24
    const unsigned short* Aptr = A + (size_t)(m0 + arow) * K + ak;
    const unsigned short* Bptr = Bt + (size_t)(n0 + arow) * K + ak;

    for (int k0 = 0; k0 < K; k0 += 32) {
        __syncthreads();
        *(u16x8*)&As[arow][ak]      = *(const u16x8*)(Aptr + k0);
        *(u16x8*)&As[arow + 64][ak] = *(const u16x8*)(Aptr + (size_t)64 * K + k0);
        *(u16x8*)&Bs[arow][ak]      = *(const u16x8*)(Bptr + k0);
        *(u16x8*)&Bs[arow + 64][ak] = *(const u16x8*)(Bptr + (size_t)64 * K + k0);
        __syncthreads();

        bf16x8 af[4], bfr[4];
#pragma unroll
        for (int m = 0; m < 4; ++m)
            af[m] = *(const bf16x8*)&As[wr + m * 16 + lc][g * 8];
#pragma unroll
        for (int n = 0; n < 4; ++n)
            bfr[n] = *(const bf16x8*)&Bs[wc + n * 16 + lc][g * 8];
#pragma unroll
        for (int m = 0; m < 4; ++m)
#pragma unroll
            for (int n = 0; n < 4; ++n)
                acc[m][n] = __builtin_amdgcn_mfma_f32_16x16x32_bf16(af[m], bfr[n], acc[m][n], 0, 0, 0);
    }

    // epilogue: C/D layout col=lane&15, row=(lane>>4)*4+i
#pragma unroll
    for (int m = 0; m < 4; ++m) {
        int rowb = m0 + wr + m * 16 + g * 4;
#pragma unroll
        for (int n = 0; n < 4; ++n) {
            int col = n0 + wc + n * 16 + lc;
            float bv = bias[col];
#pragma unroll
            for (int i = 0; i < 4; ++i) {
                float v = acc[m][n][i] + bv;
                int r = rowb + i;
                if (EPI == 0) {
                    outF[(size_t)r * N + col] = v;
                } else {
                    int which = col >> 10;
                    int c = col & 1023;
                    int h = c >> 6, d = c & 63;
                    int b = r >> 11, t = r & 2047;
                    unsigned short* dst = (which == 0) ? q_out : ((which == 1) ? k_out : v_out);
                    dst[(((size_t)b * NH + h) * T_SEQ + t) * HD + d] = f2b(v);
                }
            }
        }
    }
}

// ---------------- flash attention (causal) ----------------
// Q/K/V: bf16 [B*H][T][HD]. One block = 64 q-rows of one head; 4 waves x 16 rows.
__global__ __launch_bounds__(256) void attn_kernel(
        const unsigned short* __restrict__ Qb, const unsigned short* __restrict__ Kb,
        const unsigned short* __restrict__ Vb, unsigned short* __restrict__ Yb) {
    __shared__ alignas(16) unsigned short Kl[64][72];       // [key][d]
    __shared__ alignas(16) unsigned short Vl[64][72];       // transposed: [d][key]
    __shared__ alignas(16) unsigned short Pl[4][16][72];    // per-wave P tile [q][key]

    int tid = threadIdx.x;
    int wid = tid >> 6, lane = tid & 63;
    int g = lane >> 4, lc = lane & 15;
    int bh = blockIdx.y;
    int q0 = blockIdx.x * 64;
    size_t head_base = (size_t)bh * T_SEQ * HD;

    // Q fragment (A-operand): lane holds Q[lc][g*8 + e] per 32-k chunk
    const unsigned short* Qp = Qb + head_base + (size_t)(q0 + wid * 16 + lc) * HD;
    bf16x8 qa0 = *(const bf16x8*)(Qp + g * 8);
    bf16x8 qa1 = *(const bf16x8*)(Qp + 32 + g * 8);

    f32x4 o[4];
    float m_i[4], l_i[4];
#pragma unroll
    for (int nd = 0; nd < 4; ++nd) o[nd] = fzero4();
#pragma unroll
    for (int i = 0; i < 4; ++i) { m_i[i] = -__builtin_inff(); l_i[i] = 0.f; }

    int ks_key = tid >> 3, ks_d = (tid & 7) * 8;  // K staging
    int vk = tid & 63, vd = (tid >> 6) * 8;       // V staging (lane varies along key)

    const float SCALE = 0.125f;  // 1/sqrt(64)
    int ntiles = blockIdx.x + 1;

    for (int kt = 0; kt < ntiles; ++kt) {
        int k0 = kt * 64;
        __syncthreads();
        // stage K [key][d]
        const unsigned short* Kp = Kb + head_base + (size_t)(k0 + ks_key) * HD + ks_d;
        *(u16x8*)&Kl[ks_key][ks_d]      = *(const u16x8*)Kp;
        *(u16x8*)&Kl[ks_key + 32][ks_d] = *(const u16x8*)(Kp + 32 * HD);
        // stage V transposed [d][key]
        const unsigned short* Vp = Vb + head_base + (size_t)(k0 + vk) * HD;
        u16x8 v0 = *(const u16x8*)(Vp + vd);
        u16x8 v1 = *(const u16x8*)(Vp + vd + 32);
#pragma unroll
        for (int j = 0; j < 8; ++j) {
            Vl[vd + j][vk] = v0[j];
            Vl[vd + 32 + j][vk] = v1[j];
        }
        __syncthreads();

        // S = Q @ K^T  (16 q x 64 keys per wave)
        f32x4 s[4];
#pragma unroll
        for (int n = 0; n < 4; ++n) {
            s[n] = fzero4();
            s[n] = __builtin_amdgcn_mfma_f32_16x16x32_bf16(
                qa0, *(const bf16x8*)&Kl[n * 16 + lc][g * 8], s[n], 0, 0, 0);
            s[n] = __builtin_amdgcn_mfma_f32_16x16x32_bf16(
                qa1, *(const bf16x8*)&Kl[n * 16 + lc][32 + g * 8], s[n], 0, 0, 0);
        }

        // scale + causal mask (only the diagonal tile needs masking)
        float sv[4][4];
        bool diag = (kt == ntiles - 1);
#pragma unroll
        for (int n = 0; n < 4; ++n)
#pragma unroll
            for (int i = 0; i < 4; ++i) {
                float val = s[n][i] * SCALE;
                if (diag && (k0 + n * 16 + lc > q0 + wid * 16 + g * 4 + i))
                    val = -__builtin_inff();
                sv[n][i] = val;
            }

        // row max across 16 lanes of the group
        float pm[4];
#pragma unroll
        for (int i = 0; i < 4; ++i)
            pm[i] = fmaxf(fmaxf(sv[0][i], sv[1][i]), fmaxf(sv[2][i], sv[3][i]));
#pragma unroll
        for (int off = 1; off < 16; off <<= 1)
#pragma unroll
            for (int i = 0; i < 4; ++i)
                pm[i] = fmaxf(pm[i], __shfl_xor(pm[i], off));

        float f_[4];
#pragma unroll
        for (int i = 0; i < 4; ++i) {
            float mn = fmaxf(m_i[i], pm[i]);
            f_[i] = __expf(m_i[i] - mn);
            m_i[i] = mn;
        }

        // P = exp(S - m), write to per-wave LDS for PV A-operand
        float psum[4] = {0.f, 0.f, 0.f, 0.f};
#pragma unroll
        for (int n = 0; n < 4; ++n)
#pragma unroll
            for (int i = 0; i < 4; ++i) {
                float p = __expf(sv[n][i] - m_i[i]);  // masked -> exp(-inf)=0
                psum[i] += p;
                Pl[wid][g * 4 + i][n * 16 + lc] = f2b(p);
            }
#pragma unroll
        for (int off = 1; off < 16; off <<= 1)
#pragma unroll
            for (int i = 0; i < 4; ++i)
                psum[i] += __shfl_xor(psum[i], off);
#pragma unroll
        for (int i = 0; i < 4; ++i)
            l_i[i] = l_i[i] * f_[i] + psum[i];

        // rescale O, then O += P @ V
#pragma unroll
        for (int nd = 0; nd < 4; ++nd)
#pragma unroll
            for (int i = 0; i < 4; ++i)
                o[nd][i] *= f_[i];

        bf16x8 pa0 = *(const bf16x8*)&Pl[wid][lc][g * 8];
        bf16x8 pa1 = *(const bf16x8*)&Pl[wid][lc][32 + g * 8];
#pragma unroll
        for (int nd = 0; nd < 4; ++nd) {
            o[nd] = __builtin_amdgcn_mfma_f32_16x16x32_bf16(
                pa0, *(const bf16x8*)&Vl[nd * 16 + lc][g * 8], o[nd], 0, 0, 0);
            o[nd] = __builtin_amdgcn_mfma_f32_16x16x32_bf16(
                pa1, *(const bf16x8*)&Vl[nd * 16 + lc][32 + g * 8], o[nd], 0, 0, 0);
        }
    }

    // write y [B][T][C] bf16, head h occupies cols h*64..h*64+63
    int b = bh >> 4, h = bh & 15;
    float inv[4];
#pragma unroll
    for (int i = 0; i < 4; ++i) inv[i] = 1.0f / l_i[i];
#pragma unroll
    for (int nd = 0; nd < 4; ++nd)
#pragma unroll
        for (int i = 0; i < 4; ++i) {
            int t = q0 + wid * 16 + g * 4 + i;
            Yb[((size_t)(b * T_SEQ + t)) * CDIM + h * HD + nd * 16 + lc] =
                f2b(o[nd][i] * inv[i]);
        }
}

// ---------------- launch ----------------
extern "C" void kernel_launch(void* const* d_in, const int* in_sizes, int n_in,
                              void* d_out, int out_size, void* d_ws, size_t ws_size,
                              hipStream_t stream) {
    const float* x      = (const float*)d_in[0];
    const float* w_attn = (const float*)d_in[1];
    const float* b_attn = (const float*)d_in[2];
    const float* w_proj = (const float*)d_in[3];
    const float* b_proj = (const float*)d_in[4];
    float* out = (float*)d_out;

    // workspace layout (bytes):
    //   0         xb  : x bf16 [8192][1024]     16,777,216   (reused as yb after GEMM1)
    //   16777216  wTa : w_attn^T bf16 [3072][1024]  6,291,456
    //   23068672  wTp : w_proj^T bf16 [1024][1024]  2,097,152
    //   25165824  qb  : [64][2048][64] bf16      16,777,216
    //   41943040  kb  :                          16,777,216
    //   58720256  vb  :                          16,777,216
    //   total: 75,497,472
    char* ws = (char*)d_ws;
    unsigned short* xb  = (unsigned short*)(ws);
    unsigned short* wTa = (unsigned short*)(ws + 16777216);
    unsigned short* wTp = (unsigned short*)(ws + 23068672);
    unsigned short* qb  = (unsigned short*)(ws + 25165824);
    unsigned short* kb  = (unsigned short*)(ws + 41943040);
    unsigned short* vb  = (unsigned short*)(ws + 58720256);
    unsigned short* yb  = xb;  // alias: xb dead after GEMM1

    cast_f32_bf16_kernel<<<2048, 256, 0, stream>>>(x, xb, (NB * T_SEQ * CDIM) / 8);
    transpose_cast_kernel<<<dim3(3072 / 32, 1024 / 32), dim3(32, 8), 0, stream>>>(
        w_attn, wTa, 1024, 3072);
    transpose_cast_kernel<<<dim3(1024 / 32, 1024 / 32), dim3(32, 8), 0, stream>>>(
        w_proj, wTp, 1024, 1024);

    // QKV GEMM: [8192,1024] @ [1024,3072] -> scatter q/k/v
    gemm_bt_kernel<1><<<dim3(3072 / 128, 8192 / 128), 256, 0, stream>>>(
        xb, wTa, b_attn, nullptr, qb, kb, vb, 8192, 3072, 1024);

    // flash attention
    attn_kernel<<<dim3(T_SEQ / 64, BH), 256, 0, stream>>>(qb, kb, vb, yb);

    // proj GEMM: [8192,1024] @ [1024,1024] -> fp32 out
    gemm_bt_kernel<0><<<dim3(1024 / 128, 8192 / 128), 256, 0, stream>>>(
        yb, wTp, b_proj, out, nullptr, nullptr, nullptr, 8192, 1024, 1024);
}

// Round 2
// 265.609 us; speedup vs baseline: 1.3950x; 1.3950x over previous
//
#include <hip/hip_runtime.h>

// CausalSelfAttention: B=4, T=2048, C=1024, H=16, hd=64
// cast->bf16, QKV GEMM (MFMA), V-transpose, paired-tile flash attention, proj GEMM

#define T_SEQ 2048
#define NB 4
#define NH 16
#define CDIM 1024
#define HD 64
#define BH (NB * NH)

typedef float f32x4 __attribute__((ext_vector_type(4)));
typedef __bf16 bf16x8 __attribute__((ext_vector_type(8)));
typedef unsigned short u16x8 __attribute__((ext_vector_type(8)));

__device__ __forceinline__ unsigned short f2b(float f) {
    union { float f; unsigned u; } v; v.f = f;
    unsigned u = v.u;
    u += 0x7FFFu + ((u >> 16) & 1u);   // round-to-nearest-even
    return (unsigned short)(u >> 16);
}

__device__ __forceinline__ f32x4 fzero4() {
    f32x4 z; z[0] = 0.f; z[1] = 0.f; z[2] = 0.f; z[3] = 0.f; return z;
}

// ---------------- prep: fp32 -> bf16 cast ----------------
__global__ __launch_bounds__(256) void cast_f32_bf16_kernel(
        const float* __restrict__ in, unsigned short* __restrict__ out, int n8) {
    int i = blockIdx.x * 256 + threadIdx.x;
    int stride = gridDim.x * 256;
    for (; i < n8; i += stride) {
        const float4* p = reinterpret_cast<const float4*>(in) + (size_t)i * 2;
        float4 a = p[0], b = p[1];
        u16x8 o;
        o[0] = f2b(a.x); o[1] = f2b(a.y); o[2] = f2b(a.z); o[3] = f2b(a.w);
        o[4] = f2b(b.x); o[5] = f2b(b.y); o[6] = f2b(b.z); o[7] = f2b(b.w);
        *(reinterpret_cast<u16x8*>(out) + i) = o;
    }
}

// ---------------- prep: transpose + cast [R][C] f32 -> [C][R] bf16 ----------------
__global__ __launch_bounds__(256) void transpose_cast_kernel(
        const float* __restrict__ in, unsigned short* __restrict__ out, int R, int C) {
    __shared__ unsigned short tile[32][33];
    int tx = threadIdx.x, ty = threadIdx.y;
    int c0 = blockIdx.x * 32, r0 = blockIdx.y * 32;
    for (int rr = ty; rr < 32; rr += 8)
        tile[rr][tx] = f2b(in[(size_t)(r0 + rr) * C + c0 + tx]);
    __syncthreads();
    for (int rr = ty; rr < 32; rr += 8)
        out[(size_t)(c0 + rr) * R + r0 + tx] = tile[tx][rr];
}

// ---------------- transpose V per head: [BH][T][HD] bf16 -> [BH][HD][T] bf16 ----------------
__global__ __launch_bounds__(256) void transpose_v_kernel(
        const unsigned short* __restrict__ in, unsigned short* __restrict__ out) {
    __shared__ unsigned short tl[64][72];
    int bh = blockIdx.y;
    int t0 = blockIdx.x * 64;
    int r = threadIdx.x >> 3;          // 0..31
    int c8 = (threadIdx.x & 7) * 8;    // 0..56
    const unsigned short* src = in + ((size_t)bh * T_SEQ + t0) * HD;
    *(u16x8*)&tl[r][c8]      = *(const u16x8*)(src + (size_t)r * HD + c8);
    *(u16x8*)&tl[r + 32][c8] = *(const u16x8*)(src + (size_t)(r + 32) * HD + c8);
    __syncthreads();
    unsigned short* dst = out + (size_t)bh * HD * T_SEQ + t0;
    u16x8 a, b;
#pragma unroll
    for (int j = 0; j < 8; ++j) { a[j] = tl[c8 + j][r]; b[j] = tl[c8 + j][r + 32]; }
    *(u16x8*)(dst + (size_t)r * T_SEQ + c8)        = a;
    *(u16x8*)(dst + (size_t)(r + 32) * T_SEQ + c8) = b;
}

// ---------------- GEMM: C[M][N] = A[M][K] @ Bt[N][K]^T + bias ----------------
// EPI=0: fp32 to outF.  EPI=1: scatter bf16 q(,*0.125)/k/v into [B*H][T][HD] buffers.
template <int EPI>
__global__ __launch_bounds__(256) void gemm_bt_kernel(
        const unsigned short* __restrict__ A, const unsigned short* __restrict__ Bt,
        const float* __restrict__ bias, float* __restrict__ outF,
        unsigned short* __restrict__ q_out, unsigned short* __restrict__ k_out,
        unsigned short* __restrict__ v_out, int M, int N, int K) {
    __shared__ alignas(16) unsigned short As[128][40];
    __shared__ alignas(16) unsigned short Bs[128][40];

    int tid = threadIdx.x;
    int wid = tid >> 6, lane = tid & 63;
    int g = lane >> 4, lc = lane & 15;
    int wr = (wid >> 1) * 64, wc = (wid & 1) * 64;
    int m0 = blockIdx.y * 128, n0 = blockIdx.x * 128;

    f32x4 acc[4][4];
#pragma unroll
    for (int m = 0; m < 4; ++m)
#pragma unroll
        for (int n = 0; n < 4; ++n) acc[m][n] = fzero4();

    int arow = tid >> 2;
    int ak = (tid & 3) * 8;
    const unsigned short* Aptr = A + (size_t)(m0 + arow) * K + ak;
    const unsigned short* Bptr = Bt + (size_t)(n0 + arow) * K + ak;

    for (int k0 = 0; k0 < K; k0 += 32) {
        __syncthreads();
        *(u16x8*)&As[arow][ak]      = *(const u16x8*)(Aptr + k0);
        *(u16x8*)&As[arow + 64][ak] = *(const u16x8*)(Aptr + (size_t)64 * K + k0);
        *(u16x8*)&Bs[arow][ak]      = *(const u16x8*)(Bptr + k0);
        *(u16x8*)&Bs[arow + 64][ak] = *(const u16x8*)(Bptr + (size_t)64 * K + k0);
        __syncthreads();

        bf16x8 af[4], bfr[4];
#pragma unroll
        for (int m = 0; m < 4; ++m)
            af[m] = *(const bf16x8*)&As[wr + m * 16 + lc][g * 8];
#pragma unroll
        for (int n = 0; n < 4; ++n)
            bfr[n] = *(const bf16x8*)&Bs[wc + n * 16 + lc][g * 8];
#pragma unroll
        for (int m = 0; m < 4; ++m)
#pragma unroll
            for (int n = 0; n < 4; ++n)
                acc[m][n] = __builtin_amdgcn_mfma_f32_16x16x32_bf16(af[m], bfr[n], acc[m][n], 0, 0, 0);
    }

#pragma unroll
    for (int m = 0; m < 4; ++m) {
        int rowb = m0 + wr + m * 16 + g * 4;
#pragma unroll
        for (int n = 0; n < 4; ++n) {
            int col = n0 + wc + n * 16 + lc;
            float bv = bias[col];
#pragma unroll
            for (int i = 0; i < 4; ++i) {
                float v = acc[m][n][i] + bv;
                int r = rowb + i;
                if (EPI == 0) {
                    outF[(size_t)r * N + col] = v;
                } else {
                    int which = col >> 10;
                    int c = col & 1023;
                    int h = c >> 6, d = c & 63;
                    int b = r >> 11, t = r & 2047;
                    if (which == 0) v *= 0.125f;  // fold 1/sqrt(hd) into q (exact pow2)
                    unsigned short* dst = (which == 0) ? q_out : ((which == 1) ? k_out : v_out);
                    dst[(((size_t)b * NH + h) * T_SEQ + t) * HD + d] = f2b(v);
                }
            }
        }
    }
}

// ---------------- flash attention, paired causal q-tiles ----------------
// Block = 1 head x q-tile pair (qt, 31-qt), 64 rows each; 4 waves x 16 rows per tile.
// Every block does exactly 33 tile-computes -> perfectly balanced.
__global__ __launch_bounds__(256) void attn_pair_kernel(
        const unsigned short* __restrict__ Qb, const unsigned short* __restrict__ Kb,
        const unsigned short* __restrict__ Vt, unsigned short* __restrict__ Yb) {
    __shared__ alignas(16) unsigned short Kl[64][72];     // [key][d]
    __shared__ alignas(16) unsigned short Vl[64][72];     // [d][key] (from Vt)
    __shared__ alignas(16) unsigned short Pl[4][16][72];  // per-wave P [q][key]

    int tid = threadIdx.x;
    int wid = tid >> 6, lane = tid & 63;
    int g = lane >> 4, lc = lane & 15;
    int qt = blockIdx.x;          // 0..15 -> pair (qt, 31-qt)
    int bh = blockIdx.y;
    size_t hb = (size_t)bh * T_SEQ * HD;

    int qA0 = qt * 64 + wid * 16;
    int qB0 = (31 - qt) * 64 + wid * 16;

    const unsigned short* QA = Qb + hb + (size_t)(qA0 + lc) * HD;
    const unsigned short* QB = Qb + hb + (size_t)(qB0 + lc) * HD;
    bf16x8 qAf0 = *(const bf16x8*)(QA + g * 8);
    bf16x8 qAf1 = *(const bf16x8*)(QA + 32 + g * 8);
    bf16x8 qBf0 = *(const bf16x8*)(QB + g * 8);
    bf16x8 qBf1 = *(const bf16x8*)(QB + 32 + g * 8);

    f32x4 oA[4], oB[4];
    float mA[4], lA[4], mB[4], lB[4];
#pragma unroll
    for (int nd = 0; nd < 4; ++nd) { oA[nd] = fzero4(); oB[nd] = fzero4(); }
#pragma unroll
    for (int i = 0; i < 4; ++i) {
        mA[i] = -__builtin_inff(); lA[i] = 0.f;
        mB[i] = -__builtin_inff(); lB[i] = 0.f;
    }

    int ks_r = tid >> 3, ks_c = (tid & 7) * 8;
    int ntB = 32 - qt;

#define COMPUTE_TILE(QF0, QF1, O, MI, LI, QBASE, DIAG)                               \
    {                                                                                \
        f32x4 s[4];                                                                  \
        _Pragma("unroll")                                                            \
        for (int n = 0; n < 4; ++n) {                                                \
            s[n] = fzero4();                                                         \
            s[n] = __builtin_amdgcn_mfma_f32_16x16x32_bf16(                          \
                QF0, *(const bf16x8*)&Kl[n * 16 + lc][g * 8], s[n], 0, 0, 0);        \
            s[n] = __builtin_amdgcn_mfma_f32_16x16x32_bf16(                          \
                QF1, *(const bf16x8*)&Kl[n * 16 + lc][32 + g * 8], s[n], 0, 0, 0);   \
        }                                                                            \
        if (DIAG) {                                                                  \
            _Pragma("unroll")                                                        \
            for (int n = 0; n < 4; ++n)                                              \
                _Pragma("unroll")                                                    \
                for (int i = 0; i < 4; ++i)                                          \
                    if (k0 + n * 16 + lc > (QBASE) + g * 4 + i)                      \
                        s[n][i] = -__builtin_inff();                                 \
        }                                                                            \
        float pm[4];                                                                 \
        _Pragma("unroll")                                                            \
        for (int i = 0; i < 4; ++i)                                                  \
            pm[i] = fmaxf(fmaxf(s[0][i], s[1][i]), fmaxf(s[2][i], s[3][i]));         \
        _Pragma("unroll")                                                            \
        for (int off = 1; off < 16; off <<= 1)                                       \
            _Pragma("unroll")                                                        \
            for (int i = 0; i < 4; ++i)                                              \
                pm[i] = fmaxf(pm[i], __shfl_xor(pm[i], off));                        \
        float f_[4];                                                                 \
        _Pragma("unroll")                                                            \
        for (int i = 0; i < 4; ++i) {                                                \
            float mn = fmaxf(MI[i], pm[i]);                                          \
            f_[i] = __expf(MI[i] - mn);                                              \
            MI[i] = mn;                                                              \
        }                                                                            \
        float psum[4] = {0.f, 0.f, 0.f, 0.f};                                        \
        _Pragma("unroll")                                                            \
        for (int n = 0; n < 4; ++n)                                                  \
            _Pragma("unroll")                                                        \
            for (int i = 0; i < 4; ++i) {                                            \
                float p = __expf(s[n][i] - MI[i]);                                   \
                psum[i] += p;                                                        \
                Pl[wid][g * 4 + i][n * 16 + lc] = f2b(p);                            \
            }                                                                        \
        _Pragma("unroll")                                                            \
        for (int off = 1; off < 16; off <<= 1)                                       \
            _Pragma("unroll")                                                        \
            for (int i = 0; i < 4; ++i)                                              \
                psum[i] += __shfl_xor(psum[i], off);                                 \
        _Pragma("unroll")                                                            \
        for (int i = 0; i < 4; ++i)                                                  \
            LI[i] = LI[i] * f_[i] + psum[i];                                         \
        _Pragma("unroll")                                                            \
        for (int nd = 0; nd < 4; ++nd)                                               \
            _Pragma("unroll")                                                        \
            for (int i = 0; i < 4; ++i)                                              \
                O[nd][i] *= f_[i];                                                   \
        bf16x8 pa0 = *(const bf16x8*)&Pl[wid][lc][g * 8];                            \
        bf16x8 pa1 = *(const bf16x8*)&Pl[wid][lc][32 + g * 8];                       \
        _Pragma("unroll")                                                            \
        for (int nd = 0; nd < 4; ++nd) {                                             \
            O[nd] = __builtin_amdgcn_mfma_f32_16x16x32_bf16(                         \
                pa0, *(const bf16x8*)&Vl[nd * 16 + lc][g * 8], O[nd], 0, 0, 0);      \
            O[nd] = __builtin_amdgcn_mfma_f32_16x16x32_bf16(                         \
                pa1, *(const bf16x8*)&Vl[nd * 16 + lc][32 + g * 8], O[nd], 0, 0, 0); \
        }                                                                            \
    }

    for (int kt = 0; kt < ntB; ++kt) {
        int k0 = kt * 64;
        __syncthreads();
        // stage K [key][d]
        const unsigned short* Kp = Kb + hb + (size_t)(k0 + ks_r) * HD + ks_c;
        *(u16x8*)&Kl[ks_r][ks_c]      = *(const u16x8*)Kp;
        *(u16x8*)&Kl[ks_r + 32][ks_c] = *(const u16x8*)(Kp + 32 * HD);
        // stage V^T [d][key] (already transposed globally)
        const unsigned short* Vp = Vt + hb + (size_t)ks_r * T_SEQ + k0 + ks_c;
        *(u16x8*)&Vl[ks_r][ks_c]      = *(const u16x8*)Vp;
        *(u16x8*)&Vl[ks_r + 32][ks_c] = *(const u16x8*)(Vp + (size_t)32 * T_SEQ);
        __syncthreads();

        COMPUTE_TILE(qBf0, qBf1, oB, mB, lB, qB0, kt == ntB - 1);
        if (kt <= qt) COMPUTE_TILE(qAf0, qAf1, oA, mA, lA, qA0, kt == qt);
    }
#undef COMPUTE_TILE

    // write y [B][T][C] bf16
    int b = bh >> 4, h = bh & 15;
    float invA[4], invB[4];
#pragma unroll
    for (int i = 0; i < 4; ++i) { invA[i] = 1.0f / lA[i]; invB[i] = 1.0f / lB[i]; }
#pragma unroll
    for (int nd = 0; nd < 4; ++nd)
#pragma unroll
        for (int i = 0; i < 4; ++i) {
            int tA = qA0 + g * 4 + i;
            int tB = qB0 + g * 4 + i;
            Yb[((size_t)(b * T_SEQ + tA)) * CDIM + h * HD + nd * 16 + lc] =
                f2b(oA[nd][i] * invA[i]);
            Yb[((size_t)(b * T_SEQ + tB)) * CDIM + h * HD + nd * 16 + lc] =
                f2b(oB[nd][i] * invB[i]);
        }
}

// ---------------- launch ----------------
extern "C" void kernel_launch(void* const* d_in, const int* in_sizes, int n_in,
                              void* d_out, int out_size, void* d_ws, size_t ws_size,
                              hipStream_t stream) {
    const float* x      = (const float*)d_in[0];
    const float* w_attn = (const float*)d_in[1];
    const float* b_attn = (const float*)d_in[2];
    const float* w_proj = (const float*)d_in[3];
    const float* b_proj = (const float*)d_in[4];
    float* out = (float*)d_out;

    // workspace layout (bytes):
    //   0         xb  : x bf16 [8192][1024]         16,777,216  (reused as yb)
    //   16777216  wTa : w_attn^T bf16 [3072][1024]   6,291,456
    //   23068672  wTp : w_proj^T bf16 [1024][1024]   2,097,152
    //   25165824  qb  : [64][2048][64] bf16         16,777,216  (pre-scaled by 0.125)
    //   41943040  kb  : [64][2048][64] bf16         16,777,216
    //   58720256  vTb : [64][64][2048] bf16         16,777,216  (V transposed per head)
    //   total: 75,497,472
    // v (un-transposed) is scattered into d_out (33.5MB fp32 buffer, used as bf16 scratch)
    char* ws = (char*)d_ws;
    unsigned short* xb  = (unsigned short*)(ws);
    unsigned short* wTa = (unsigned short*)(ws + 16777216);
    unsigned short* wTp = (unsigned short*)(ws + 23068672);
    unsigned short* qb  = (unsigned short*)(ws + 25165824);
    unsigned short* kb  = (unsigned short*)(ws + 41943040);
    unsigned short* vTb = (unsigned short*)(ws + 58720256);
    unsigned short* yb  = xb;                       // alias: xb dead after GEMM1
    unsigned short* vtmp = (unsigned short*)d_out;  // scratch until final GEMM

    cast_f32_bf16_kernel<<<2048, 256, 0, stream>>>(x, xb, (NB * T_SEQ * CDIM) / 8);
    transpose_cast_kernel<<<dim3(3072 / 32, 1024 / 32), dim3(32, 8), 0, stream>>>(
        w_attn, wTa, 1024, 3072);
    transpose_cast_kernel<<<dim3(1024 / 32, 1024 / 32), dim3(32, 8), 0, stream>>>(
        w_proj, wTp, 1024, 1024);

    // QKV GEMM: scatter q (scaled), k, v
    gemm_bt_kernel<1><<<dim3(3072 / 128, 8192 / 128), 256, 0, stream>>>(
        xb, wTa, b_attn, nullptr, qb, kb, vtmp, 8192, 3072, 1024);

    // V -> V^T per head
    transpose_v_kernel<<<dim3(T_SEQ / 64, BH), 256, 0, stream>>>(vtmp, vTb);

    // paired-tile flash attention
    attn_pair_kernel<<<dim3(16, BH), 256, 0, stream>>>(qb, kb, vTb, yb);

    // proj GEMM -> fp32 out
    gemm_bt_kernel<0><<<dim3(1024 / 128, 8192 / 128), 256, 0, stream>>>(
        yb, wTp, b_proj, out, nullptr, nullptr, nullptr, 8192, 1024, 1024);
}

// Round 3
// 242.822 us; speedup vs baseline: 1.5259x; 1.0938x over previous
//
#include <hip/hip_runtime.h>

// CausalSelfAttention: B=4, T=2048, C=1024, H=16, hd=64
// cast->bf16, QKV GEMM (global_load_lds), V-transpose, swapped-QK^T flash attention, proj GEMM

#define T_SEQ 2048
#define NB 4
#define NH 16
#define CDIM 1024
#define HD 64
#define BH (NB * NH)

typedef float f32x4 __attribute__((ext_vector_type(4)));
typedef __bf16 bf16x8 __attribute__((ext_vector_type(8)));
typedef unsigned short u16x8 __attribute__((ext_vector_type(8)));

__device__ __forceinline__ unsigned short f2b(float f) {
    union { float f; unsigned u; } v; v.f = f;
    unsigned u = v.u;
    u += 0x7FFFu + ((u >> 16) & 1u);   // round-to-nearest-even
    return (unsigned short)(u >> 16);
}

__device__ __forceinline__ f32x4 fzero4() {
    f32x4 z; z[0] = 0.f; z[1] = 0.f; z[2] = 0.f; z[3] = 0.f; return z;
}

// async global->LDS, 16B per lane. LDS dest is wave-uniform base + lane*16 (HW rule).
__device__ __forceinline__ void gld16(const void* gp, void* lp) {
    __builtin_amdgcn_global_load_lds(
        (const __attribute__((address_space(1))) unsigned int*)gp,
        (__attribute__((address_space(3))) unsigned int*)lp, 16, 0, 0);
}

// ---------------- prep: fp32 -> bf16 cast ----------------
__global__ __launch_bounds__(256) void cast_f32_bf16_kernel(
        const float* __restrict__ in, unsigned short* __restrict__ out, int n8) {
    int i = blockIdx.x * 256 + threadIdx.x;
    int stride = gridDim.x * 256;
    for (; i < n8; i += stride) {
        const float4* p = reinterpret_cast<const float4*>(in) + (size_t)i * 2;
        float4 a = p[0], b = p[1];
        u16x8 o;
        o[0] = f2b(a.x); o[1] = f2b(a.y); o[2] = f2b(a.z); o[3] = f2b(a.w);
        o[4] = f2b(b.x); o[5] = f2b(b.y); o[6] = f2b(b.z); o[7] = f2b(b.w);
        *(reinterpret_cast<u16x8*>(out) + i) = o;
    }
}

// ---------------- prep: transpose + cast [R][C] f32 -> [C][R] bf16 ----------------
__global__ __launch_bounds__(256) void transpose_cast_kernel(
        const float* __restrict__ in, unsigned short* __restrict__ out, int R, int C) {
    __shared__ unsigned short tile[32][33];
    int tx = threadIdx.x, ty = threadIdx.y;
    int c0 = blockIdx.x * 32, r0 = blockIdx.y * 32;
    for (int rr = ty; rr < 32; rr += 8)
        tile[rr][tx] = f2b(in[(size_t)(r0 + rr) * C + c0 + tx]);
    __syncthreads();
    for (int rr = ty; rr < 32; rr += 8)
        out[(size_t)(c0 + rr) * R + r0 + tx] = tile[tx][rr];
}

// ---------------- transpose V per head: [BH][T][HD] -> [BH][HD][T] ----------------
__global__ __launch_bounds__(256) void transpose_v_kernel(
        const unsigned short* __restrict__ in, unsigned short* __restrict__ out) {
    __shared__ unsigned short tl[64][72];
    int bh = blockIdx.y;
    int t0 = blockIdx.x * 64;
    int r = threadIdx.x >> 3;          // 0..31
    int c8 = (threadIdx.x & 7) * 8;    // 0..56
    const unsigned short* src = in + ((size_t)bh * T_SEQ + t0) * HD;
    *(u16x8*)&tl[r][c8]      = *(const u16x8*)(src + (size_t)r * HD + c8);
    *(u16x8*)&tl[r + 32][c8] = *(const u16x8*)(src + (size_t)(r + 32) * HD + c8);
    __syncthreads();
    unsigned short* dst = out + (size_t)bh * HD * T_SEQ + t0;
    u16x8 a, b;
#pragma unroll
    for (int j = 0; j < 8; ++j) { a[j] = tl[c8 + j][r]; b[j] = tl[c8 + j][r + 32]; }
    *(u16x8*)(dst + (size_t)r * T_SEQ + c8)        = a;
    *(u16x8*)(dst + (size_t)(r + 32) * T_SEQ + c8) = b;
}

// ---------------- GEMM: C[M][N] = A[M][K] @ Bt[N][K]^T + bias ----------------
// Staging via global_load_lds width=16 into linear [128][32] LDS (m97 ladder step 3).
// EPI=0: fp32 to outF.  EPI=1: scatter bf16 q(*0.125)/k/v into [B*H][T][HD] buffers.
template <int EPI>
__global__ __launch_bounds__(256) void gemm_bt_kernel(
        const unsigned short* __restrict__ A, const unsigned short* __restrict__ Bt,
        const float* __restrict__ bias, float* __restrict__ outF,
        unsigned short* __restrict__ q_out, unsigned short* __restrict__ k_out,
        unsigned short* __restrict__ v_out, int M, int N, int K) {
    __shared__ alignas(16) unsigned short As[128][32];  // linear: gld16 requires it
    __shared__ alignas(16) unsigned short Bs[128][32];

    int tid = threadIdx.x;
    int wid = tid >> 6, lane = tid & 63;
    int g = lane >> 4, lc = lane & 15;
    int wr = (wid >> 1) * 64, wc = (wid & 1) * 64;
    int m0 = blockIdx.y * 128, n0 = blockIdx.x * 128;

    f32x4 acc[4][4];
#pragma unroll
    for (int m = 0; m < 4; ++m)
#pragma unroll
        for (int n = 0; n < 4; ++n) acc[m][n] = fzero4();

    // staging: thread t covers linear LDS bytes t*16 -> row t/4, col (t%4)*8
    int srow = tid >> 2;            // 0..63
    int scol = (tid & 3) * 8;
    const unsigned short* Ap = A + (size_t)(m0 + srow) * K + scol;
    const unsigned short* Bp = Bt + (size_t)(n0 + srow) * K + scol;
    unsigned short* lA0 = &As[wid * 16][0];       // wave-uniform bases
    unsigned short* lA1 = &As[64 + wid * 16][0];
    unsigned short* lB0 = &Bs[wid * 16][0];
    unsigned short* lB1 = &Bs[64 + wid * 16][0];

    for (int k0 = 0; k0 < K; k0 += 32) {
        __syncthreads();
        gld16(Ap + k0, lA0);
        gld16(Ap + (size_t)64 * K + k0, lA1);
        gld16(Bp + k0, lB0);
        gld16(Bp + (size_t)64 * K + k0, lB1);
        __syncthreads();  // drains vmcnt -> LDS visible

        bf16x8 af[4], bfr[4];
#pragma unroll
        for (int m = 0; m < 4; ++m)
            af[m] = *(const bf16x8*)&As[wr + m * 16 + lc][g * 8];
#pragma unroll
        for (int n = 0; n < 4; ++n)
            bfr[n] = *(const bf16x8*)&Bs[wc + n * 16 + lc][g * 8];
#pragma unroll
        for (int m = 0; m < 4; ++m)
#pragma unroll
            for (int n = 0; n < 4; ++n)
                acc[m][n] = __builtin_amdgcn_mfma_f32_16x16x32_bf16(af[m], bfr[n], acc[m][n], 0, 0, 0);
    }

#pragma unroll
    for (int m = 0; m < 4; ++m) {
        int rowb = m0 + wr + m * 16 + g * 4;
#pragma unroll
        for (int n = 0; n < 4; ++n) {
            int col = n0 + wc + n * 16 + lc;
            float bv = bias[col];
#pragma unroll
            for (int i = 0; i < 4; ++i) {
                float v = acc[m][n][i] + bv;
                int r = rowb + i;
                if (EPI == 0) {
                    outF[(size_t)r * N + col] = v;
                } else {
                    int which = col >> 10;
                    int c = col & 1023;
                    int h = c >> 6, d = c & 63;
                    int b = r >> 11, t = r & 2047;
                    if (which == 0) v *= 0.125f;  // fold 1/sqrt(hd) into q (exact pow2)
                    unsigned short* dst = (which == 0) ? q_out : ((which == 1) ? k_out : v_out);
                    dst[(((size_t)b * NH + h) * T_SEQ + t) * HD + d] = f2b(v);
                }
            }
        }
    }
}

// ---------------- flash attention, swapped QK^T, paired causal q-tiles ----------------
// Block = 1 head x q-tile pair (qt, 31-qt); 4 waves x 16 q-rows per tile.
// Swapped mfma(K,Q) -> S^T[key][q]: lane owns 16 keys of ONE query (q = lane&15).
// Softmax: in-lane tree + 2 shfls. P->PV A-frag via cvt_pk + 16 bpermute (no LDS).
__global__ __launch_bounds__(256) void attn_pair_kernel(
        const unsigned short* __restrict__ Qb, const unsigned short* __restrict__ Kb,
        const unsigned short* __restrict__ Vt, unsigned short* __restrict__ Yb) {
    __shared__ alignas(16) unsigned short Kl[64][72];   // [key][d]
    __shared__ alignas(16) unsigned short Vl[64][72];   // [d][key]

    int tid = threadIdx.x;
    int wid = tid >> 6, lane = tid & 63;
    int g = lane >> 4, lc = lane & 15;
    int hi = g >> 1;
    int src0 = ((g & 1) << 5) + lc;   // ((g&1)*2)*16 + lc
    int src1 = src0 + 16;

    // bijective XCD swizzle: 1024 blocks, 8 XCDs -> each XCD owns 8 whole heads
    int id = blockIdx.x;
    int swz = (id & 7) * 128 + (id >> 3);
    int bh = swz >> 4;
    int qt = swz & 15;                // pair (qt, 31-qt)
    size_t hb = (size_t)bh * T_SEQ * HD;

    int qA0 = qt * 64 + wid * 16;
    int qB0 = (31 - qt) * 64 + wid * 16;

    const unsigned short* QA = Qb + hb + (size_t)(qA0 + lc) * HD;
    const unsigned short* QB = Qb + hb + (size_t)(qB0 + lc) * HD;
    bf16x8 qAf0 = *(const bf16x8*)(QA + g * 8);
    bf16x8 qAf1 = *(const bf16x8*)(QA + 32 + g * 8);
    bf16x8 qBf0 = *(const bf16x8*)(QB + g * 8);
    bf16x8 qBf1 = *(const bf16x8*)(QB + 32 + g * 8);

    f32x4 oA[4], oB[4];
    float mA = -__builtin_inff(), lA = 0.f;
    float mB = -__builtin_inff(), lB = 0.f;
#pragma unroll
    for (int nd = 0; nd < 4; ++nd) { oA[nd] = fzero4(); oB[nd] = fzero4(); }

    int ks_r = tid >> 3, ks_c = (tid & 7) * 8;
    int ntB = 32 - qt;
    const float LOG2E = 1.44269504088896f;

// s_[n][i] = S^T[key = k0 + n*16 + g*4 + i][q = QBASE + lc]
#define COMPUTE_TILE(QF0, QF1, O, MI, LI, QBASE, DIAG)                               \
    {                                                                                \
        f32x4 s_[4];                                                                 \
        __builtin_amdgcn_s_setprio(1);                                               \
        _Pragma("unroll")                                                            \
        for (int n = 0; n < 4; ++n) {                                                \
            s_[n] = fzero4();                                                        \
            s_[n] = __builtin_amdgcn_mfma_f32_16x16x32_bf16(                         \
                *(const bf16x8*)&Kl[n * 16 + lc][g * 8], QF0, s_[n], 0, 0, 0);       \
            s_[n] = __builtin_amdgcn_mfma_f32_16x16x32_bf16(                         \
                *(const bf16x8*)&Kl[n * 16 + lc][32 + g * 8], QF1, s_[n], 0, 0, 0);  \
        }                                                                            \
        __builtin_amdgcn_s_setprio(0);                                               \
        int qg_ = (QBASE) + lc;                                                      \
        _Pragma("unroll")                                                            \
        for (int n = 0; n < 4; ++n)                                                  \
            _Pragma("unroll")                                                        \
            for (int i = 0; i < 4; ++i) {                                            \
                float v_ = s_[n][i] * LOG2E;                                         \
                if ((DIAG) && (k0 + n * 16 + g * 4 + i > qg_))                       \
                    v_ = -__builtin_inff();                                          \
                s_[n][i] = v_;                                                       \
            }                                                                        \
        float r8_[8], r4_[4], pm_;                                                   \
        _Pragma("unroll")                                                            \
        for (int j = 0; j < 8; ++j)                                                  \
            r8_[j] = fmaxf(s_[j >> 2][j & 3], s_[(j + 8) >> 2][(j + 8) & 3]);        \
        _Pragma("unroll")                                                            \
        for (int j = 0; j < 4; ++j) r4_[j] = fmaxf(r8_[j], r8_[j + 4]);              \
        pm_ = fmaxf(fmaxf(r4_[0], r4_[1]), fmaxf(r4_[2], r4_[3]));                   \
        pm_ = fmaxf(pm_, __shfl_xor(pm_, 16));                                       \
        pm_ = fmaxf(pm_, __shfl_xor(pm_, 32));                                       \
        float mn_ = fmaxf(MI, pm_);                                                  \
        float f_ = __builtin_amdgcn_exp2f(MI - mn_);                                 \
        MI = mn_;                                                                    \
        _Pragma("unroll")                                                            \
        for (int n = 0; n < 4; ++n)                                                  \
            _Pragma("unroll")                                                        \
            for (int i = 0; i < 4; ++i)                                              \
                s_[n][i] = __builtin_amdgcn_exp2f(s_[n][i] - mn_);                   \
        float q8_[8], q4_[4], ps_;                                                   \
        _Pragma("unroll")                                                            \
        for (int j = 0; j < 8; ++j)                                                  \
            q8_[j] = s_[j >> 2][j & 3] + s_[(j + 8) >> 2][(j + 8) & 3];              \
        _Pragma("unroll")                                                            \
        for (int j = 0; j < 4; ++j) q4_[j] = q8_[j] + q8_[j + 4];                    \
        ps_ = (q4_[0] + q4_[1]) + (q4_[2] + q4_[3]);                                 \
        ps_ += __shfl_xor(ps_, 16);                                                  \
        ps_ += __shfl_xor(ps_, 32);                                                  \
        LI = LI * f_ + ps_;                                                          \
        unsigned pk_[8];                                                             \
        _Pragma("unroll")                                                            \
        for (int n = 0; n < 4; ++n)                                                  \
            _Pragma("unroll")                                                        \
            for (int d = 0; d < 2; ++d)                                              \
                asm("v_cvt_pk_bf16_f32 %0, %1, %2"                                   \
                    : "=v"(pk_[n * 2 + d])                                           \
                    : "v"(s_[n][2 * d]), "v"(s_[n][2 * d + 1]));                     \
        _Pragma("unroll")                                                            \
        for (int i = 0; i < 4; ++i) {                                                \
            float fo_ = __shfl(f_, g * 4 + i);                                       \
            _Pragma("unroll")                                                        \
            for (int nd = 0; nd < 4; ++nd) O[nd][i] *= fo_;                          \
        }                                                                            \
        _Pragma("unroll")                                                            \
        for (int c = 0; c < 2; ++c) {                                                \
            union { unsigned u[4]; bf16x8 v; } pu_;                                  \
            _Pragma("unroll")                                                        \
            for (int j = 0; j < 2; ++j) {                                            \
                int sl_ = j ? src1 : src0;                                           \
                _Pragma("unroll")                                                    \
                for (int d = 0; d < 2; ++d) {                                        \
                    unsigned a_ = __shfl(pk_[c * 4 + d], sl_);                       \
                    unsigned b_ = __shfl(pk_[c * 4 + 2 + d], sl_);                   \
                    pu_.u[j * 2 + d] = hi ? b_ : a_;                                 \
                }                                                                    \
            }                                                                        \
            __builtin_amdgcn_s_setprio(1);                                           \
            _Pragma("unroll")                                                        \
            for (int nd = 0; nd < 4; ++nd)                                           \
                O[nd] = __builtin_amdgcn_mfma_f32_16x16x32_bf16(                     \
                    pu_.v, *(const bf16x8*)&Vl[nd * 16 + lc][c * 32 + g * 8],        \
                    O[nd], 0, 0, 0);                                                 \
            __builtin_amdgcn_s_setprio(0);                                           \
        }                                                                            \
    }

    for (int kt = 0; kt < ntB; ++kt) {
        int k0 = kt * 64;
        __syncthreads();
        // stage K [key][d]
        const unsigned short* Kp = Kb + hb + (size_t)(k0 + ks_r) * HD + ks_c;
        *(u16x8*)&Kl[ks_r][ks_c]      = *(const u16x8*)Kp;
        *(u16x8*)&Kl[ks_r + 32][ks_c] = *(const u16x8*)(Kp + 32 * HD);
        // stage V^T [d][key]
        const unsigned short* Vp = Vt + hb + (size_t)ks_r * T_SEQ + k0 + ks_c;
        *(u16x8*)&Vl[ks_r][ks_c]      = *(const u16x8*)Vp;
        *(u16x8*)&Vl[ks_r + 32][ks_c] = *(const u16x8*)(Vp + (size_t)32 * T_SEQ);
        __syncthreads();

        COMPUTE_TILE(qBf0, qBf1, oB, mB, lB, qB0, kt == ntB - 1);
        if (kt <= qt) COMPUTE_TILE(qAf0, qAf1, oA, mA, lA, qA0, kt == qt);
    }
#undef COMPUTE_TILE

    // write y [B][T][C] bf16 (O rows: q = Q0 + g*4+i, cols: d = nd*16+lc)
    int b = bh >> 4, h = bh & 15;
    float invA[4], invB[4];
#pragma unroll
    for (int i = 0; i < 4; ++i) {
        invA[i] = 1.0f / __shfl(lA, g * 4 + i);
        invB[i] = 1.0f / __shfl(lB, g * 4 + i);
    }
#pragma unroll
    for (int nd = 0; nd < 4; ++nd)
#pragma unroll
        for (int i = 0; i < 4; ++i) {
            int tA = qA0 + g * 4 + i;
            int tB = qB0 + g * 4 + i;
            Yb[((size_t)(b * T_SEQ + tA)) * CDIM + h * HD + nd * 16 + lc] =
                f2b(oA[nd][i] * invA[i]);
            Yb[((size_t)(b * T_SEQ + tB)) * CDIM + h * HD + nd * 16 + lc] =
                f2b(oB[nd][i] * invB[i]);
        }
}

// ---------------- launch ----------------
extern "C" void kernel_launch(void* const* d_in, const int* in_sizes, int n_in,
                              void* d_out, int out_size, void* d_ws, size_t ws_size,
                              hipStream_t stream) {
    const float* x      = (const float*)d_in[0];
    const float* w_attn = (const float*)d_in[1];
    const float* b_attn = (const float*)d_in[2];
    const float* w_proj = (const float*)d_in[3];
    const float* b_proj = (const float*)d_in[4];
    float* out = (float*)d_out;

    // workspace layout (bytes):
    //   0         xb  : x bf16 [8192][1024]         16,777,216  (reused as yb)
    //   16777216  wTa : w_attn^T bf16 [3072][1024]   6,291,456
    //   23068672  wTp : w_proj^T bf16 [1024][1024]   2,097,152
    //   25165824  qb  : [64][2048][64] bf16         16,777,216  (pre-scaled by 0.125)
    //   41943040  kb  : [64][2048][64] bf16         16,777,216
    //   58720256  vTb : [64][64][2048] bf16         16,777,216  (V transposed per head)
    // v (un-transposed) scratch lives in d_out until the final GEMM overwrites it.
    char* ws = (char*)d_ws;
    unsigned short* xb  = (unsigned short*)(ws);
    unsigned short* wTa = (unsigned short*)(ws + 16777216);
    unsigned short* wTp = (unsigned short*)(ws + 23068672);
    unsigned short* qb  = (unsigned short*)(ws + 25165824);
    unsigned short* kb  = (unsigned short*)(ws + 41943040);
    unsigned short* vTb = (unsigned short*)(ws + 58720256);
    unsigned short* yb  = xb;                       // alias: xb dead after GEMM1
    unsigned short* vtmp = (unsigned short*)d_out;  // scratch until final GEMM

    cast_f32_bf16_kernel<<<2048, 256, 0, stream>>>(x, xb, (NB * T_SEQ * CDIM) / 8);
    transpose_cast_kernel<<<dim3(3072 / 32, 1024 / 32), dim3(32, 8), 0, stream>>>(
        w_attn, wTa, 1024, 3072);
    transpose_cast_kernel<<<dim3(1024 / 32, 1024 / 32), dim3(32, 8), 0, stream>>>(
        w_proj, wTp, 1024, 1024);

    // QKV GEMM: scatter q (scaled), k, v
    gemm_bt_kernel<1><<<dim3(3072 / 128, 8192 / 128), 256, 0, stream>>>(
        xb, wTa, b_attn, nullptr, qb, kb, vtmp, 8192, 3072, 1024);

    // V -> V^T per head
    transpose_v_kernel<<<dim3(T_SEQ / 64, BH), 256, 0, stream>>>(vtmp, vTb);

    // swapped-QK^T paired flash attention (1D grid for XCD swizzle)
    attn_pair_kernel<<<dim3(16 * BH), 256, 0, stream>>>(qb, kb, vTb, yb);

    // proj GEMM -> fp32 out
    gemm_bt_kernel<0><<<dim3(1024 / 128, 8192 / 128), 256, 0, stream>>>(
        yb, wTp, b_proj, out, nullptr, nullptr, nullptr, 8192, 1024, 1024);
}

// Round 4
// 195.826 us; speedup vs baseline: 1.8922x; 1.2400x over previous
//
#include <hip/hip_runtime.h>

// CausalSelfAttention: B=4, T=2048, C=1024, H=16, hd=64
// cast->bf16, QKV GEMM (global_load_lds, writes V^T directly),
// 32x32-MFMA swapped-QK^T flash attention (lane-local softmax), proj GEMM

#define T_SEQ 2048
#define NB 4
#define NH 16
#define CDIM 1024
#define HD 64
#define BH (NB * NH)
#define QSCALE 0.1803368801111204f  // 0.125 * log2(e): fold 1/sqrt(hd) and exp2 conversion into q

typedef float f32x4 __attribute__((ext_vector_type(4)));
typedef float f32x16 __attribute__((ext_vector_type(16)));
typedef __bf16 bf16x8 __attribute__((ext_vector_type(8)));
typedef unsigned short u16x8 __attribute__((ext_vector_type(8)));
typedef unsigned short u16x4 __attribute__((ext_vector_type(4)));

__device__ __forceinline__ unsigned short f2b(float f) {
    union { float f; unsigned u; } v; v.f = f;
    unsigned u = v.u;
    u += 0x7FFFu + ((u >> 16) & 1u);   // round-to-nearest-even
    return (unsigned short)(u >> 16);
}

__device__ __forceinline__ f32x4 fzero4() {
    f32x4 z; z[0] = 0.f; z[1] = 0.f; z[2] = 0.f; z[3] = 0.f; return z;
}

__device__ __forceinline__ f32x16 mfma32(bf16x8 a, bf16x8 b, f32x16 c) {
    return __builtin_amdgcn_mfma_f32_32x32x16_bf16(a, b, c, 0, 0, 0);
}

// async global->LDS, 16B/lane; LDS dest = wave-uniform base + lane*16 (HW rule)
__device__ __forceinline__ void gld16(const void* gp, void* lp) {
    __builtin_amdgcn_global_load_lds(
        (const __attribute__((address_space(1))) unsigned int*)gp,
        (__attribute__((address_space(3))) unsigned int*)lp, 16, 0, 0);
}

// ---------------- prep: fp32 -> bf16 cast ----------------
__global__ __launch_bounds__(256) void cast_f32_bf16_kernel(
        const float* __restrict__ in, unsigned short* __restrict__ out, int n8) {
    int i = blockIdx.x * 256 + threadIdx.x;
    int stride = gridDim.x * 256;
    for (; i < n8; i += stride) {
        const float4* p = reinterpret_cast<const float4*>(in) + (size_t)i * 2;
        float4 a = p[0], b = p[1];
        u16x8 o;
        o[0] = f2b(a.x); o[1] = f2b(a.y); o[2] = f2b(a.z); o[3] = f2b(a.w);
        o[4] = f2b(b.x); o[5] = f2b(b.y); o[6] = f2b(b.z); o[7] = f2b(b.w);
        *(reinterpret_cast<u16x8*>(out) + i) = o;
    }
}

// ---------------- prep: transpose + cast [R][C] f32 -> [C][R] bf16 ----------------
__global__ __launch_bounds__(256) void transpose_cast_kernel(
        const float* __restrict__ in, unsigned short* __restrict__ out, int R, int C) {
    __shared__ unsigned short tile[32][33];
    int tx = threadIdx.x, ty = threadIdx.y;
    int c0 = blockIdx.x * 32, r0 = blockIdx.y * 32;
    for (int rr = ty; rr < 32; rr += 8)
        tile[rr][tx] = f2b(in[(size_t)(r0 + rr) * C + c0 + tx]);
    __syncthreads();
    for (int rr = ty; rr < 32; rr += 8)
        out[(size_t)(c0 + rr) * R + r0 + tx] = tile[tx][rr];
}

// ---------------- GEMM: C[M][N] = A[M][K] @ Bt[N][K]^T + bias ----------------
// EPI=0: fp32 to outF. EPI=1: scatter q(*QSCALE)/k to [BH][T][HD], v to V^T [BH][HD][T].
template <int EPI>
__global__ __launch_bounds__(256) void gemm_bt_kernel(
        const unsigned short* __restrict__ A, const unsigned short* __restrict__ Bt,
        const float* __restrict__ bias, float* __restrict__ outF,
        unsigned short* __restrict__ q_out, unsigned short* __restrict__ k_out,
        unsigned short* __restrict__ v_out, int M, int N, int K) {
    __shared__ alignas(16) unsigned short As[128][32];  // linear: gld16 requires it
    __shared__ alignas(16) unsigned short Bs[128][32];

    int tid = threadIdx.x;
    int wid = tid >> 6, lane = tid & 63;
    int g = lane >> 4, lc = lane & 15;
    int wr = (wid >> 1) * 64, wc = (wid & 1) * 64;
    int m0 = blockIdx.y * 128, n0 = blockIdx.x * 128;

    f32x4 acc[4][4];
#pragma unroll
    for (int m = 0; m < 4; ++m)
#pragma unroll
        for (int n = 0; n < 4; ++n) acc[m][n] = fzero4();

    int srow = tid >> 2;
    int scol = (tid & 3) * 8;
    const unsigned short* Ap = A + (size_t)(m0 + srow) * K + scol;
    const unsigned short* Bp = Bt + (size_t)(n0 + srow) * K + scol;
    unsigned short* lA0 = &As[wid * 16][0];
    unsigned short* lA1 = &As[64 + wid * 16][0];
    unsigned short* lB0 = &Bs[wid * 16][0];
    unsigned short* lB1 = &Bs[64 + wid * 16][0];

    for (int k0 = 0; k0 < K; k0 += 32) {
        __syncthreads();
        gld16(Ap + k0, lA0);
        gld16(Ap + (size_t)64 * K + k0, lA1);
        gld16(Bp + k0, lB0);
        gld16(Bp + (size_t)64 * K + k0, lB1);
        __syncthreads();

        bf16x8 af[4], bfr[4];
#pragma unroll
        for (int m = 0; m < 4; ++m)
            af[m] = *(const bf16x8*)&As[wr + m * 16 + lc][g * 8];
#pragma unroll
        for (int n = 0; n < 4; ++n)
            bfr[n] = *(const bf16x8*)&Bs[wc + n * 16 + lc][g * 8];
#pragma unroll
        for (int m = 0; m < 4; ++m)
#pragma unroll
            for (int n = 0; n < 4; ++n)
                acc[m][n] = __builtin_amdgcn_mfma_f32_16x16x32_bf16(af[m], bfr[n], acc[m][n], 0, 0, 0);
    }

#pragma unroll
    for (int m = 0; m < 4; ++m) {
        int rowb = m0 + wr + m * 16 + g * 4;
#pragma unroll
        for (int n = 0; n < 4; ++n) {
            int col = n0 + wc + n * 16 + lc;
            float bv = bias[col];
            if (EPI == 0) {
#pragma unroll
                for (int i = 0; i < 4; ++i)
                    outF[(size_t)(rowb + i) * N + col] = acc[m][n][i] + bv;
            } else {
                int which = col >> 10;
                int c = col & 1023;
                int h = c >> 6, d = c & 63;
                int bh_ = (rowb >> 11) * NH + h;
                int tl = rowb & 2047;  // rowb multiple of 4, stays in batch
                if (which == 2) {
                    u16x4 vq;
#pragma unroll
                    for (int i = 0; i < 4; ++i) vq[i] = f2b(acc[m][n][i] + bv);
                    *(u16x4*)&v_out[(size_t)bh_ * (HD * T_SEQ) + (size_t)d * T_SEQ + tl] = vq;
                } else {
                    unsigned short* dst = which ? k_out : q_out;
                    float sc = which ? 1.0f : QSCALE;
#pragma unroll
                    for (int i = 0; i < 4; ++i)
                        dst[((size_t)bh_ * T_SEQ + tl + i) * HD + d] =
                            f2b((acc[m][n][i] + bv) * sc);
                }
            }
        }
    }
}

// ---------------- flash attention: 32x32 MFMA, swapped QK^T, wave-level pairs ----------------
// Grid 512 blocks x 256 thr. Wave p = b8*4+wid owns q-tiles (p, 63-p) of 32 rows each.
// S^T = mfma(K,Q): lane owns q = lane&31, 32 keys in regs -> lane-local softmax.
// K/V LDS [64][64] XOR-swizzled (slot ^= row&7), staged via gld16 w/ pre-swizzled source.
__global__ __launch_bounds__(256) void attn32_kernel(
        const unsigned short* __restrict__ Qb, const unsigned short* __restrict__ Kb,
        const unsigned short* __restrict__ Vt, unsigned short* __restrict__ Yb) {
    __shared__ alignas(16) unsigned short Kl[64 * 64];  // [key][d], swizzled
    __shared__ alignas(16) unsigned short Vl[64 * 64];  // [d][key], swizzled

    int tid = threadIdx.x;
    int wid = tid >> 6, lane = tid & 63;
    int ql = lane & 31, hi = lane >> 5;
    int ql7 = ql & 7;

    // XCD swizzle: 512 blocks -> each XCD owns 8 whole heads
    int id = blockIdx.x;
    int swz = (id & 7) * 64 + (id >> 3);
    int bh = swz >> 3;
    int b8 = swz & 7;
    int p = b8 * 4 + wid;             // wave's pair (p, 63-p)
    size_t hb = (size_t)bh * (T_SEQ * HD);

    int qA0 = p * 32, qB0 = (63 - p) * 32;
    int ktA = p >> 1;
    int ktB = 31 - (p >> 1);
    int nt = 32 - 2 * b8;
    { int alt = 2 * b8 + 2; if (alt > nt) nt = alt; }

    // persistent Q B-frag for tile B (col=q=ql, elems d = dstep*16 + hi*8 + e)
    bf16x8 qB_[4];
    const unsigned short* QBp = Qb + hb + (size_t)(qB0 + ql) * HD + hi * 8;
#pragma unroll
    for (int d = 0; d < 4; ++d) qB_[d] = *(const bf16x8*)(QBp + d * 16);
    const unsigned short* QAp = Qb + hb + (size_t)(qA0 + ql) * HD + hi * 8;

    f32x16 zz;
#pragma unroll
    for (int r = 0; r < 16; ++r) zz[r] = 0.f;
    f32x16 oA0 = zz, oA1 = zz, oB0 = zz, oB1 = zz;
    float mA = -__builtin_inff(), lA = 0.f;
    float mB = -__builtin_inff(), lB = 0.f;

    // staging: lane covers LDS slot (row = 8-row-group + lane>>3, slot' = lane&7);
    // source pre-swizzled: global slot = slot' ^ (row&7)
    int r8 = lane >> 3;
    int sslot = (lane & 7) ^ r8;
    const unsigned short* Kg = Kb + hb + (size_t)(wid * 16 + r8) * HD + sslot * 8;
    const unsigned short* Vg = Vt + hb + (size_t)(wid * 16 + r8) * T_SEQ + sslot * 8;
    char* KlB = (char*)Kl + wid * 2048;
    char* VlB = (char*)Vl + wid * 2048;

#define KF(K0, D) (*(const bf16x8*)&Kl[(((K0)*32 + ql) << 6) + ((((D)*2 + hi) ^ ql7) << 3)])
#define VF(DB, T) (*(const bf16x8*)&Vl[(((DB)*32 + ql) << 6) + ((((T)*2 + hi) ^ ql7) << 3)])

// one 32q x 64k tile-compute. s_[r] <-> key = 32*K0 + 8*(r>>2) + (r&3) + 4*hi, q = Q0+ql
#define TILE(QF, O0, O1, MI, LI, Q0, DIAG)                                           \
    {                                                                                \
        f32x16 s0_, s1_;                                                             \
        __builtin_amdgcn_s_setprio(1);                                               \
        s0_ = mfma32(KF(0, 0), QF[0], zz);                                           \
        s0_ = mfma32(KF(0, 1), QF[1], s0_);                                          \
        s0_ = mfma32(KF(0, 2), QF[2], s0_);                                          \
        s0_ = mfma32(KF(0, 3), QF[3], s0_);                                          \
        s1_ = mfma32(KF(1, 0), QF[0], zz);                                           \
        s1_ = mfma32(KF(1, 1), QF[1], s1_);                                          \
        s1_ = mfma32(KF(1, 2), QF[2], s1_);                                          \
        s1_ = mfma32(KF(1, 3), QF[3], s1_);                                          \
        __builtin_amdgcn_s_setprio(0);                                               \
        if (DIAG) {                                                                  \
            int qg_ = (Q0) + ql;                                                     \
            _Pragma("unroll")                                                        \
            for (int r = 0; r < 16; ++r) {                                           \
                int kof_ = k0 + 8 * (r >> 2) + (r & 3) + 4 * hi;                     \
                if (kof_ > qg_) s0_[r] = -__builtin_inff();                          \
                if (kof_ + 32 > qg_) s1_[r] = -__builtin_inff();                     \
            }                                                                        \
        }                                                                            \
        float t_[8];                                                                 \
        _Pragma("unroll")                                                            \
        for (int r = 0; r < 8; ++r)                                                  \
            t_[r] = fmaxf(fmaxf(s0_[r], s0_[r + 8]), fmaxf(s1_[r], s1_[r + 8]));     \
        _Pragma("unroll")                                                            \
        for (int r = 0; r < 4; ++r) t_[r] = fmaxf(t_[r], t_[r + 4]);                 \
        float pm_ = fmaxf(fmaxf(t_[0], t_[1]), fmaxf(t_[2], t_[3]));                 \
        pm_ = fmaxf(pm_, __shfl_xor(pm_, 32));                                       \
        float mn_ = fmaxf(MI, pm_);                                                  \
        float f_ = __builtin_amdgcn_exp2f(MI - mn_);                                 \
        MI = mn_;                                                                    \
        _Pragma("unroll")                                                            \
        for (int r = 0; r < 16; ++r) {                                               \
            s0_[r] = __builtin_amdgcn_exp2f(s0_[r] - mn_);                           \
            s1_[r] = __builtin_amdgcn_exp2f(s1_[r] - mn_);                           \
        }                                                                            \
        float u_[8];                                                                 \
        _Pragma("unroll")                                                            \
        for (int r = 0; r < 8; ++r)                                                  \
            u_[r] = (s0_[r] + s0_[r + 8]) + (s1_[r] + s1_[r + 8]);                   \
        _Pragma("unroll")                                                            \
        for (int r = 0; r < 4; ++r) u_[r] += u_[r + 4];                              \
        float ps_ = (u_[0] + u_[1]) + (u_[2] + u_[3]);                               \
        ps_ += __shfl_xor(ps_, 32);                                                  \
        LI = LI * f_ + ps_;                                                          \
        O0 *= f_;                                                                    \
        O1 *= f_;                                                                    \
        unsigned pw_[16];                                                            \
        _Pragma("unroll")                                                            \
        for (int K0 = 0; K0 < 2; ++K0) {                                             \
            _Pragma("unroll")                                                        \
            for (int h2 = 0; h2 < 2; ++h2) {                                         \
                float e0_, e1_, e2_, e3_, e4_, e5_, e6_, e7_;                        \
                if (K0 == 0) {                                                       \
                    e0_ = s0_[8 * h2 + 0]; e1_ = s0_[8 * h2 + 1];                    \
                    e2_ = s0_[8 * h2 + 2]; e3_ = s0_[8 * h2 + 3];                    \
                    e4_ = s0_[8 * h2 + 4]; e5_ = s0_[8 * h2 + 5];                    \
                    e6_ = s0_[8 * h2 + 6]; e7_ = s0_[8 * h2 + 7];                    \
                } else {                                                             \
                    e0_ = s1_[8 * h2 + 0]; e1_ = s1_[8 * h2 + 1];                    \
                    e2_ = s1_[8 * h2 + 2]; e3_ = s1_[8 * h2 + 3];                    \
                    e4_ = s1_[8 * h2 + 4]; e5_ = s1_[8 * h2 + 5];                    \
                    e6_ = s1_[8 * h2 + 6]; e7_ = s1_[8 * h2 + 7];                    \
                }                                                                    \
                unsigned a_, b_, c_, d_;                                             \
                asm("v_cvt_pk_bf16_f32 %0, %1, %2" : "=v"(a_) : "v"(e0_), "v"(e1_)); \
                asm("v_cvt_pk_bf16_f32 %0, %1, %2" : "=v"(b_) : "v"(e2_), "v"(e3_)); \
                asm("v_cvt_pk_bf16_f32 %0, %1, %2" : "=v"(c_) : "v"(e4_), "v"(e5_)); \
                asm("v_cvt_pk_bf16_f32 %0, %1, %2" : "=v"(d_) : "v"(e6_), "v"(e7_)); \
                asm("v_permlane32_swap_b32 %0, %1" : "+v"(a_), "+v"(c_));            \
                asm("v_permlane32_swap_b32 %0, %1" : "+v"(b_), "+v"(d_));            \
                pw_[(K0 * 2 + h2) * 4 + 0] = a_;                                     \
                pw_[(K0 * 2 + h2) * 4 + 1] = b_;                                     \
                pw_[(K0 * 2 + h2) * 4 + 2] = c_;                                     \
                pw_[(K0 * 2 + h2) * 4 + 3] = d_;                                     \
            }                                                                        \
        }                                                                            \
        __builtin_amdgcn_s_setprio(1);                                               \
        _Pragma("unroll")                                                            \
        for (int t = 0; t < 4; ++t) {                                                \
            union { unsigned u[4]; bf16x8 v; } pf_;                                  \
            pf_.u[0] = pw_[t * 4 + 0]; pf_.u[1] = pw_[t * 4 + 1];                    \
            pf_.u[2] = pw_[t * 4 + 2]; pf_.u[3] = pw_[t * 4 + 3];                    \
            O0 = mfma32(VF(0, t), pf_.v, O0);                                        \
            O1 = mfma32(VF(1, t), pf_.v, O1);                                        \
        }                                                                            \
        __builtin_amdgcn_s_setprio(0);                                               \
    }

    for (int kt = 0; kt < nt; ++kt) {
        int k0 = kt * 64;
        __syncthreads();
        gld16(Kg + (size_t)k0 * HD, KlB);
        gld16(Kg + (size_t)(k0 + 8) * HD, KlB + 1024);
        gld16(Vg + k0, VlB);
        gld16(Vg + k0 + 8 * T_SEQ, VlB + 1024);
        __syncthreads();

        bool doA = (kt <= ktA);
        bf16x8 qA_[4];
        if (doA) {
#pragma unroll
            for (int d = 0; d < 4; ++d) qA_[d] = *(const bf16x8*)(QAp + d * 16);
        }
        if (kt <= ktB) TILE(qB_, oB0, oB1, mB, lB, qB0, kt == ktB);
        if (doA) TILE(qA_, oA0, oA1, mA, lA, qA0, kt == ktA);
    }
#undef TILE
#undef KF
#undef VF

    // epilogue: O^T[d][q]: q = Q0+ql (lane), d = dblk*32 + 8a + (0..3) + 4hi per reg quad
    int bb = bh >> 4, h = bh & 15;
    float ivA = 1.0f / lA, ivB = 1.0f / lB;
#pragma unroll
    for (int dblk = 0; dblk < 2; ++dblk) {
#pragma unroll
        for (int a = 0; a < 4; ++a) {
            u16x4 wA, wB;
#pragma unroll
            for (int i = 0; i < 4; ++i) {
                float vA = (dblk ? oA1[4 * a + i] : oA0[4 * a + i]) * ivA;
                float vB = (dblk ? oB1[4 * a + i] : oB0[4 * a + i]) * ivB;
                wA[i] = f2b(vA);
                wB[i] = f2b(vB);
            }
            int dq = dblk * 32 + 8 * a + 4 * hi;
            *(u16x4*)&Yb[((size_t)(bb * T_SEQ + qA0 + ql)) * CDIM + h * HD + dq] = wA;
            *(u16x4*)&Yb[((size_t)(bb * T_SEQ + qB0 + ql)) * CDIM + h * HD + dq] = wB;
        }
    }
}

// ---------------- launch ----------------
extern "C" void kernel_launch(void* const* d_in, const int* in_sizes, int n_in,
                              void* d_out, int out_size, void* d_ws, size_t ws_size,
                              hipStream_t stream) {
    const float* x      = (const float*)d_in[0];
    const float* w_attn = (const float*)d_in[1];
    const float* b_attn = (const float*)d_in[2];
    const float* w_proj = (const float*)d_in[3];
    const float* b_proj = (const float*)d_in[4];
    float* out = (float*)d_out;

    // workspace layout (bytes):
    //   0         xb  : x bf16 [8192][1024]         16,777,216  (reused as yb)
    //   16777216  wTa : w_attn^T bf16 [3072][1024]   6,291,456
    //   23068672  wTp : w_proj^T bf16 [1024][1024]   2,097,152
    //   25165824  qb  : [64][2048][64] bf16         16,777,216  (pre-scaled by QSCALE)
    //   41943040  kb  : [64][2048][64] bf16         16,777,216
    //   58720256  vTb : [64][64][2048] bf16         16,777,216  (V^T, written by GEMM1)
    char* ws = (char*)d_ws;
    unsigned short* xb  = (unsigned short*)(ws);
    unsigned short* wTa = (unsigned short*)(ws + 16777216);
    unsigned short* wTp = (unsigned short*)(ws + 23068672);
    unsigned short* qb  = (unsigned short*)(ws + 25165824);
    unsigned short* kb  = (unsigned short*)(ws + 41943040);
    unsigned short* vTb = (unsigned short*)(ws + 58720256);
    unsigned short* yb  = xb;  // alias: xb dead after GEMM1

    cast_f32_bf16_kernel<<<2048, 256, 0, stream>>>(x, xb, (NB * T_SEQ * CDIM) / 8);
    transpose_cast_kernel<<<dim3(3072 / 32, 1024 / 32), dim3(32, 8), 0, stream>>>(
        w_attn, wTa, 1024, 3072);
    transpose_cast_kernel<<<dim3(1024 / 32, 1024 / 32), dim3(32, 8), 0, stream>>>(
        w_proj, wTp, 1024, 1024);

    // QKV GEMM: q (scaled), k row-major; v written transposed per head
    gemm_bt_kernel<1><<<dim3(3072 / 128, 8192 / 128), 256, 0, stream>>>(
        xb, wTa, b_attn, nullptr, qb, kb, vTb, 8192, 3072, 1024);

    // flash attention (1D grid for XCD swizzle)
    attn32_kernel<<<dim3(512), 256, 0, stream>>>(qb, kb, vTb, yb);

    // proj GEMM -> fp32 out
    gemm_bt_kernel<0><<<dim3(1024 / 128, 8192 / 128), 256, 0, stream>>>(
        yb, wTp, b_proj, out, nullptr, nullptr, nullptr, 8192, 1024, 1024);
}